// Round 1
// baseline (63.258 us; speedup 1.0000x reference)
//
#include <hip/hip_runtime.h>
#include <hip/hip_bf16.h>

// Problem: B=N=1024, in_f=1024, OUT_F=32, KD=8
// out[n][0:1024]   = x[n][:]
// M[n][o*8+k]      = sum_f x[n][f] * T[f][o*8+k]        (T flat [1024][256])
// out[n][1024+o]   = sum_{i != n} exp(-sum_k |M[i][o*8+k] - M[n][o*8+k]|)

#define N_ROWS 1024
#define IN_F   1024
#define OUT_C  1056
#define OK     256   // OUT_F*KD

// ---------------- kernel 1: strided copy of x into out ----------------
__global__ __launch_bounds__(256) void copy_x_kernel(
    const float* __restrict__ x, float* __restrict__ out) {
  int n = blockIdx.x;          // 0..1023
  int c = threadIdx.x * 4;     // 256 threads * 4 floats = 1024
  float4 v = *reinterpret_cast<const float4*>(x + (size_t)n * IN_F + c);
  *reinterpret_cast<float4*>(out + (size_t)n * OUT_C + c) = v;
}

// ---------------- kernel 2: fp32 GEMM  M[1024][256] = x @ T ----------------
// 32x32 tiles, 256 threads, 2x2 per thread. grid = (32 mtiles, 8 ntiles) = 256 blocks.
#define BK 16
__global__ __launch_bounds__(256) void gemm32_kernel(
    const float* __restrict__ A,   // [1024][1024]
    const float* __restrict__ Bm,  // [1024][256]
    float* __restrict__ M) {       // [1024][256]
  __shared__ float as[BK][32];   // k-major A tile
  __shared__ float bs[BK][32];
  int m0 = blockIdx.x * 32;
  int n0 = blockIdx.y * 32;
  int t  = threadIdx.x;
  int ty = t >> 4, tx = t & 15;       // 16x16 thread grid
  float c00 = 0.f, c01 = 0.f, c10 = 0.f, c11 = 0.f;

  for (int k0 = 0; k0 < IN_F; k0 += BK) {
    if (t < 128) {
      // stage A: 32 rows x 16 cols, one float4 per thread, transpose to k-major
      int row = t >> 2, q = t & 3;
      float4 v = *reinterpret_cast<const float4*>(A + (size_t)(m0 + row) * IN_F + k0 + q * 4);
      as[q * 4 + 0][row] = v.x;
      as[q * 4 + 1][row] = v.y;
      as[q * 4 + 2][row] = v.z;
      as[q * 4 + 3][row] = v.w;
    } else {
      // stage B: 16 rows x 32 cols, one float4 per thread
      int tt = t - 128;
      int row = tt >> 3, q = tt & 7;
      float4 v = *reinterpret_cast<const float4*>(Bm + (size_t)(k0 + row) * OK + n0 + q * 4);
      *reinterpret_cast<float4*>(&bs[row][q * 4]) = v;
    }
    __syncthreads();
#pragma unroll
    for (int kk = 0; kk < BK; ++kk) {
      float2 a = *reinterpret_cast<const float2*>(&as[kk][ty * 2]);
      float2 b = *reinterpret_cast<const float2*>(&bs[kk][tx * 2]);
      c00 += a.x * b.x; c01 += a.x * b.y;
      c10 += a.y * b.x; c11 += a.y * b.y;
    }
    __syncthreads();
  }
  int r = m0 + ty * 2, c = n0 + tx * 2;
  M[(size_t)r * OK + c]           = c00;
  M[(size_t)r * OK + c + 1]       = c01;
  M[(size_t)(r + 1) * OK + c]     = c10;
  M[(size_t)(r + 1) * OK + c + 1] = c11;
}

// ---------------- kernel 3: pairwise exp(-L1) reduction ----------------
// grid = (o: 32, jt: 16) = 512 blocks, 256 threads.
// thread = jl (0..63) + 64*s ; j = jt*64+jl ; i-range [s*256, s*256+256)
__global__ __launch_bounds__(256) void pairwise_kernel(
    const float* __restrict__ M,   // [1024][256]
    float* __restrict__ out) {
  __shared__ float sm[N_ROWS][8];   // 32 KB: M[:, o, :]
  __shared__ float red[4][64];

  int o  = blockIdx.x;   // 0..31
  int jt = blockIdx.y;   // 0..15
  int t  = threadIdx.x;

  // stage the o-slice: 1024 rows x 8 floats = 2048 float4 halves
#pragma unroll
  for (int idx = t; idx < 2048; idx += 256) {
    int row = idx >> 1, half = idx & 1;
    *reinterpret_cast<float4*>(&sm[row][half * 4]) =
        *reinterpret_cast<const float4*>(M + (size_t)row * OK + o * 8 + half * 4);
  }
  __syncthreads();

  int jl = t & 63, s = t >> 6;
  int j  = jt * 64 + jl;

  float4 ra = *reinterpret_cast<const float4*>(&sm[j][0]);
  float4 rb = *reinterpret_cast<const float4*>(&sm[j][4]);

  float acc = 0.f;
  int i0 = s * 256;
  for (int i = i0; i < i0 + 256; ++i) {
    float4 va = *reinterpret_cast<const float4*>(&sm[i][0]);
    float4 vb = *reinterpret_cast<const float4*>(&sm[i][4]);
    float d = fabsf(va.x - ra.x) + fabsf(va.y - ra.y) +
              fabsf(va.z - ra.z) + fabsf(va.w - ra.w) +
              fabsf(vb.x - rb.x) + fabsf(vb.y - rb.y) +
              fabsf(vb.z - rb.z) + fabsf(vb.w - rb.w);
    acc += __expf(-d);
  }
  // remove the exact self term (exp(-0) == 1) from the slice that contains i==j
  if ((j >> 8) == s) acc -= 1.0f;

  red[s][jl] = acc;
  __syncthreads();

  if (t < 64) {
    float v = red[0][t] + red[1][t] + red[2][t] + red[3][t];
    int jj = jt * 64 + t;
    out[(size_t)jj * OUT_C + 1024 + o] = v;
  }
}

extern "C" void kernel_launch(void* const* d_in, const int* in_sizes, int n_in,
                              void* d_out, int out_size, void* d_ws, size_t ws_size,
                              hipStream_t stream) {
  const float* x = (const float*)d_in[0];   // [1024][1024]
  const float* T = (const float*)d_in[1];   // [1024][32][8] -> [1024][256]
  float* out = (float*)d_out;               // [1024][1056]
  float* M   = (float*)d_ws;                // [1024][256] fp32 = 1 MB scratch

  copy_x_kernel<<<dim3(N_ROWS), dim3(256), 0, stream>>>(x, out);
  gemm32_kernel<<<dim3(32, 8), dim3(256), 0, stream>>>(x, T, M);
  pairwise_kernel<<<dim3(32, 16), dim3(256), 0, stream>>>(M, out);
}

// Round 2
// 46.100 us; speedup vs baseline: 1.3722x; 1.3722x over previous
//
#include <hip/hip_runtime.h>
#include <hip/hip_bf16.h>

// Problem: B=N=1024, in_f=1024, OUT_F=32, KD=8
// out[n][0:1024]   = x[n][:]
// M[n][o*8+k]      = sum_f x[n][f] * T[f][o*8+k]        (T flat [1024][256])
// out[n][1024+o]   = sum_{i != n} exp(-sum_k |M[i][o*8+k] - M[n][o*8+k]|)

#define N_ROWS 1024
#define IN_F   1024
#define OUT_C  1056
#define OK     256   // OUT_F*KD
#define KS     8     // K-split factor
#define KC     128   // K-chunk = IN_F/KS

// ---------------- kernel 1: strided copy of x into out ----------------
__global__ __launch_bounds__(256) void copy_x_kernel(
    const float* __restrict__ x, float* __restrict__ out) {
  int n = blockIdx.x;          // 0..1023
  int c = threadIdx.x * 4;     // 256 threads * 4 floats = 1024
  float4 v = *reinterpret_cast<const float4*>(x + (size_t)n * IN_F + c);
  *reinterpret_cast<float4*>(out + (size_t)n * OUT_C + c) = v;
}

// ---------------- kernel 2: fp32 GEMM with K-split ----------------
// part[ks][1024][256]; block (bm,bn,ks) computes 64x64 tile over K-chunk 128.
// One-shot LDS staging, ONE barrier, then pure compute (4x4 per thread).
__global__ __launch_bounds__(256) void gemm_split_kernel(
    const float* __restrict__ A,   // x [1024][1024]
    const float* __restrict__ Bm,  // T [1024][256]
    float* __restrict__ part) {    // [KS][1024][256]
  __shared__ float as[64][KC + 4];   // +4 pad: A-reads 2-way (free), b128-aligned
  __shared__ float bs[KC][64];
  const int m0 = blockIdx.x * 64;
  const int n0 = blockIdx.y * 64;
  const int ks = blockIdx.z;
  const int k0 = ks * KC;
  const int t  = threadIdx.x;

  // stage A: 64 rows x 128 k = 2048 float4, 8 per thread, coalesced
#pragma unroll
  for (int u = 0; u < 8; ++u) {
    int f = t + 256 * u;
    int row = f >> 5, fk = f & 31;           // KC/4 = 32 float4 per row
    float4 v = *reinterpret_cast<const float4*>(A + (size_t)(m0 + row) * IN_F + k0 + fk * 4);
    *reinterpret_cast<float4*>(&as[row][fk * 4]) = v;
  }
  // stage B: 128 k x 64 cols = 2048 float4, 16 per row, coalesced
#pragma unroll
  for (int u = 0; u < 8; ++u) {
    int f = t + 256 * u;
    int row = f >> 4, fc = f & 15;
    float4 v = *reinterpret_cast<const float4*>(Bm + (size_t)(k0 + row) * OK + n0 + fc * 4);
    *reinterpret_cast<float4*>(&bs[row][fc * 4]) = v;
  }
  __syncthreads();

  const int ty = t >> 4, tx = t & 15;   // 16x16 thread grid, 4x4 outputs each
  float acc[4][4] = {};

  for (int kk = 0; kk < KC; kk += 4) {
    float av[4][4], bv[4][4];            // av[r][i]=A[row r][kk+i], bv[i][c]=B[kk+i][col c]
#pragma unroll
    for (int r = 0; r < 4; ++r)
      *reinterpret_cast<float4*>(av[r]) = *reinterpret_cast<const float4*>(&as[ty * 4 + r][kk]);
#pragma unroll
    for (int i = 0; i < 4; ++i)
      *reinterpret_cast<float4*>(bv[i]) = *reinterpret_cast<const float4*>(&bs[kk + i][tx * 4]);
#pragma unroll
    for (int i = 0; i < 4; ++i)
#pragma unroll
      for (int r = 0; r < 4; ++r)
#pragma unroll
        for (int c = 0; c < 4; ++c)
          acc[r][c] = fmaf(av[r][i], bv[i][c], acc[r][c]);
  }

  float* dst = part + (size_t)ks * N_ROWS * OK;
#pragma unroll
  for (int r = 0; r < 4; ++r)
    *reinterpret_cast<float4*>(&dst[(size_t)(m0 + ty * 4 + r) * OK + n0 + tx * 4]) =
        *reinterpret_cast<const float4*>(acc[r]);
}

// ---------------- kernel 2b: reduce K-split partials ----------------
__global__ __launch_bounds__(256) void reduce_kernel(
    const float* __restrict__ part, float* __restrict__ M) {
  int g = blockIdx.x * 256 + threadIdx.x;         // 65536 float4 groups
  const float4* p = reinterpret_cast<const float4*>(part);
  float4 s = p[g];
#pragma unroll
  for (int sl = 1; sl < KS; ++sl) {
    float4 v = p[g + (size_t)sl * (N_ROWS * OK / 4)];
    s.x += v.x; s.y += v.y; s.z += v.z; s.w += v.w;
  }
  reinterpret_cast<float4*>(M)[g] = s;
}

// ---------------- fallback GEMM (small ws): previous single-pass ----------------
#define BK 16
__global__ __launch_bounds__(256) void gemm32_kernel(
    const float* __restrict__ A, const float* __restrict__ Bm, float* __restrict__ M) {
  __shared__ float as[BK][32];
  __shared__ float bs[BK][32];
  int m0 = blockIdx.x * 32;
  int n0 = blockIdx.y * 32;
  int t  = threadIdx.x;
  int ty = t >> 4, tx = t & 15;
  float c00 = 0.f, c01 = 0.f, c10 = 0.f, c11 = 0.f;
  for (int k0 = 0; k0 < IN_F; k0 += BK) {
    if (t < 128) {
      int row = t >> 2, q = t & 3;
      float4 v = *reinterpret_cast<const float4*>(A + (size_t)(m0 + row) * IN_F + k0 + q * 4);
      as[q * 4 + 0][row] = v.x; as[q * 4 + 1][row] = v.y;
      as[q * 4 + 2][row] = v.z; as[q * 4 + 3][row] = v.w;
    } else {
      int tt = t - 128;
      int row = tt >> 3, q = tt & 7;
      float4 v = *reinterpret_cast<const float4*>(Bm + (size_t)(k0 + row) * OK + n0 + q * 4);
      *reinterpret_cast<float4*>(&bs[row][q * 4]) = v;
    }
    __syncthreads();
#pragma unroll
    for (int kk = 0; kk < BK; ++kk) {
      float2 a = *reinterpret_cast<const float2*>(&as[kk][ty * 2]);
      float2 b = *reinterpret_cast<const float2*>(&bs[kk][tx * 2]);
      c00 += a.x * b.x; c01 += a.x * b.y;
      c10 += a.y * b.x; c11 += a.y * b.y;
    }
    __syncthreads();
  }
  int r = m0 + ty * 2, c = n0 + tx * 2;
  M[(size_t)r * OK + c]           = c00;
  M[(size_t)r * OK + c + 1]       = c01;
  M[(size_t)(r + 1) * OK + c]     = c10;
  M[(size_t)(r + 1) * OK + c + 1] = c11;
}

// ---------------- kernel 3: pairwise exp(-L1) reduction ----------------
// grid = (o: 32, jt: 16) = 512 blocks, 256 threads.
__global__ __launch_bounds__(256) void pairwise_kernel(
    const float* __restrict__ M, float* __restrict__ out) {
  __shared__ float sm[N_ROWS][8];   // 32 KB: M[:, o, :]
  __shared__ float red[4][64];

  int o  = blockIdx.x;
  int jt = blockIdx.y;
  int t  = threadIdx.x;

#pragma unroll
  for (int idx = t; idx < 2048; idx += 256) {
    int row = idx >> 1, half = idx & 1;
    *reinterpret_cast<float4*>(&sm[row][half * 4]) =
        *reinterpret_cast<const float4*>(M + (size_t)row * OK + o * 8 + half * 4);
  }
  __syncthreads();

  int jl = t & 63, s = t >> 6;
  int j  = jt * 64 + jl;

  float4 ra = *reinterpret_cast<const float4*>(&sm[j][0]);
  float4 rb = *reinterpret_cast<const float4*>(&sm[j][4]);

  float acc = 0.f;
  int i0 = s * 256;
  for (int i = i0; i < i0 + 256; ++i) {
    float4 va = *reinterpret_cast<const float4*>(&sm[i][0]);
    float4 vb = *reinterpret_cast<const float4*>(&sm[i][4]);
    float d = fabsf(va.x - ra.x) + fabsf(va.y - ra.y) +
              fabsf(va.z - ra.z) + fabsf(va.w - ra.w) +
              fabsf(vb.x - rb.x) + fabsf(vb.y - rb.y) +
              fabsf(vb.z - rb.z) + fabsf(vb.w - rb.w);
    // exp(-d) < e^-30: contributes < 1e-10 total over 1024 terms -> skip
    if (d < 30.f) acc += __expf(-d);
  }
  if ((j >> 8) == s) acc -= 1.0f;   // exact self term exp(0)=1

  red[s][jl] = acc;
  __syncthreads();

  if (t < 64) {
    float v = red[0][t] + red[1][t] + red[2][t] + red[3][t];
    int jj = jt * 64 + t;
    out[(size_t)jj * OUT_C + 1024 + o] = v;
  }
}

extern "C" void kernel_launch(void* const* d_in, const int* in_sizes, int n_in,
                              void* d_out, int out_size, void* d_ws, size_t ws_size,
                              hipStream_t stream) {
  const float* x = (const float*)d_in[0];   // [1024][1024]
  const float* T = (const float*)d_in[1];   // [1024][256]
  float* out = (float*)d_out;               // [1024][1056]

  copy_x_kernel<<<dim3(N_ROWS), dim3(256), 0, stream>>>(x, out);

  const size_t mBytes    = (size_t)N_ROWS * OK * sizeof(float);   // 1 MB
  const size_t partBytes = (size_t)KS * mBytes;                   // 8 MB

  if (ws_size >= partBytes + mBytes) {
    float* part = (float*)d_ws;
    float* M    = (float*)((char*)d_ws + partBytes);
    gemm_split_kernel<<<dim3(16, 4, KS), dim3(256), 0, stream>>>(x, T, part);
    reduce_kernel<<<dim3(256), dim3(256), 0, stream>>>(part, M);
    pairwise_kernel<<<dim3(32, 16), dim3(256), 0, stream>>>(M, out);
  } else {
    float* M = (float*)d_ws;
    gemm32_kernel<<<dim3(32, 8), dim3(256), 0, stream>>>(x, T, M);
    pairwise_kernel<<<dim3(32, 16), dim3(256), 0, stream>>>(M, out);
  }
}